// Round 8
// baseline (157.260 us; speedup 1.0000x reference)
//
#include <hip/hip_runtime.h>
#include <math.h>

#define N_PATHS 23
#define HIDDEN  32
#define N_NODES 4096
#define N_EDGES 8192
#define FEAT    512
#define EB      4     // edges per block (2 per wave)
#define BLK     128   // 2 waves
#define ZERO_BLOCKS 256

// wave-local LDS phase separator
#define WAVE_SYNC() asm volatile("s_waitcnt lgkmcnt(0)" ::: "memory")

typedef __attribute__((ext_vector_type(8))) short bf16x8;
typedef __attribute__((ext_vector_type(4))) float f32x4;

// ---- path metadata (PATHS enumeration order: l1 outer, l2, l3) ----
__device__ const int P_L1[N_PATHS] = {0,0,0,0, 1,1,1,1,1,1, 2,2,2,2,2,2,2, 3,3,3,3,3,3};
__device__ const int P_L2[N_PATHS] = {0,1,2,3, 0,1,1,2,2,3, 0,1,1,2,2,3,3, 0,1,2,2,3,3};
__device__ const int P_L3[N_PATHS] = {0,1,2,3, 1,0,2,1,3,2, 2,1,3,0,2,1,3, 3,2,1,3,0,2};
__device__ const int C_OFF[N_PATHS] = {0,1,10,35,84,93,102,147,192,297,402,427,472,577,602,727,832,1077,1126,1231,1336,1581,1630};
__device__ const int CNT_L3[4] = {4,6,7,6};
// paths grouped by l3
__device__ const int L3PATHS[N_PATHS] = {0,5,13,21, 1,4,7,11,15,19, 2,6,9,10,14,18,22, 3,8,12,16,17,20};
__device__ const int L3START[5] = {0,4,10,17,23};
__device__ const int OFF3[4] = {0,32,128,288};

// ---- 16-point Gauss-Legendre nodes/weights ----
__device__ const double GLX[16] = {
    -0.98940093499164993, -0.94457502307323258, -0.86563120238783174, -0.75540440835500303,
    -0.61787624440264375, -0.45801677765722739, -0.28160355077925891, -0.09501250983763744,
     0.09501250983763744,  0.28160355077925891,  0.45801677765722739,  0.61787624440264375,
     0.75540440835500303,  0.86563120238783174,  0.94457502307323258,  0.98940093499164993};
__device__ const double GLW[16] = {
     0.02715245941175409,  0.06225352393864789,  0.09515851168249278,  0.12462897125553387,
     0.14959598881657673,  0.16915651939500254,  0.18260341504492359,  0.18945061045506850,
     0.18945061045506850,  0.18260341504492359,  0.16915651939500254,  0.14959598881657673,
     0.12462897125553387,  0.09515851168249278,  0.06225352393864789,  0.02715245941175409};

// cos/sin(k*pi/16), exact literals
__device__ const double COSP[32] = {
  1.0,                    0.980785280403230449,  0.923879532511286756,  0.831469612302545237,
  0.707106781186547524,   0.555570233019602225,  0.382683432365089772,  0.195090322016128268,
  0.0,                   -0.195090322016128268, -0.382683432365089772, -0.555570233019602225,
 -0.707106781186547524,  -0.831469612302545237, -0.923879532511286756, -0.980785280403230449,
 -1.0,                   -0.980785280403230449, -0.923879532511286756, -0.831469612302545237,
 -0.707106781186547524,  -0.555570233019602225, -0.382683432365089772, -0.195090322016128268,
  0.0,                    0.195090322016128268,  0.382683432365089772,  0.555570233019602225,
  0.707106781186547524,   0.831469612302545237,  0.923879532511286756,  0.980785280403230449};
__device__ const double SINP[32] = {
  0.0,                    0.195090322016128268,  0.382683432365089772,  0.555570233019602225,
  0.707106781186547524,   0.831469612302545237,  0.923879532511286756,  0.980785280403230449,
  1.0,                    0.980785280403230449,  0.923879532511286756,  0.831469612302545237,
  0.707106781186547524,   0.555570233019602225,  0.382683432365089772,  0.195090322016128268,
  0.0,                   -0.195090322016128268, -0.382683432365089772, -0.555570233019602225,
 -0.707106781186547524,  -0.831469612302545237, -0.923879532511286756, -0.980785280403230449,
 -1.0,                   -0.980785280403230449, -0.923879532511286756, -0.831469612302545237,
 -0.707106781186547524,  -0.555570233019602225, -0.382683432365089772, -0.195090322016128268};

__device__ inline void sh_f64(double x, double y, double z, double* Y) {
    const double s3 = 1.7320508075688772935, s5 = 2.2360679774997896964,
                 s7 = 2.6457513110645905905, s15 = 3.8729833462074168852;
    const double c58 = 0.79056941504209483300, c38 = 0.61237243569579452455;
    Y[0] = 1.0;
    Y[1] = s3*x;  Y[2] = s3*y;  Y[3] = s3*z;
    Y[4] = s5*s3*x*z;  Y[5] = s5*s3*x*y;
    Y[6] = s5*(y*y - 0.5*(x*x + z*z));
    Y[7] = s5*s3*y*z;  Y[8] = s5*(s3/2.0)*(z*z - x*x);
    Y[9] = s7*c58*x*(3.0*z*z - x*x);
    Y[10]= s7*s15*x*y*z;
    Y[11]= s7*c38*x*(5.0*y*y - 1.0);
    Y[12]= s7*0.5*y*(5.0*y*y - 3.0);
    Y[13]= s7*c38*z*(5.0*y*y - 1.0);
    Y[14]= s7*(s15/2.0)*y*(z*z - x*x);
    Y[15]= s7*c58*z*(z*z - 3.0*x*x);
}

__device__ inline void sh_f32(float x, float y, float z, float* Y) {
    const float s3 = 1.73205080757f, s5 = 2.23606797750f, s7 = 2.64575131106f, s15 = 3.87298334621f;
    const float c58 = 0.79056941504f, c38 = 0.61237243570f;
    Y[0] = 1.0f;
    Y[1] = s3*x;  Y[2] = s3*y;  Y[3] = s3*z;
    Y[4] = s15*x*z;  Y[5] = s15*x*y;
    Y[6] = s5*(y*y - 0.5f*(x*x + z*z));
    Y[7] = s15*y*z;  Y[8] = s5*(s3*0.5f)*(z*z - x*x);
    Y[9] = s7*c58*x*(3.0f*z*z - x*x);
    Y[10]= s7*s15*x*y*z;
    Y[11]= s7*c38*x*(5.0f*y*y - 1.0f);
    Y[12]= s7*0.5f*y*(5.0f*y*y - 3.0f);
    Y[13]= s7*c38*z*(5.0f*y*y - 1.0f);
    Y[14]= s7*(s15*0.5f)*y*(z*z - x*x);
    Y[15]= s7*c58*z*(z*z - 3.0f*x*x);
}

__device__ inline unsigned short bf16rne(float x) {
    unsigned int u = __float_as_uint(x);
    unsigned int r = (u + 0x7FFFu + ((u >> 16) & 1u)) >> 16;
    return (unsigned short)r;
}
__device__ inline float bf16f(unsigned short h) {
    return __uint_as_float(((unsigned int)h) << 16);
}

// ---- setup: W3J tables + weight transpose + output zeroing (3-in-1) ----
__global__ __launch_bounds__(512) void w3j_setup_kernel(
    const float* __restrict__ ww, const float* __restrict__ wb,
    float* __restrict__ g_w3j,
    unsigned short* __restrict__ Awhi, unsigned short* __restrict__ Awlo,
    unsigned short* __restrict__ Abhi, unsigned short* __restrict__ Ablo,
    float* __restrict__ out) {
    const int t = threadIdx.x;

    // zero-blocks: clear the output buffer (replaces hipMemsetAsync dispatch)
    if (blockIdx.x >= N_PATHS) {
        const int b = blockIdx.x - N_PATHS;
        float4* o4 = (float4*)(out + (size_t)b * (N_NODES*FEAT/ZERO_BLOCKS));
#pragma unroll
        for (int r = 0; r < 4; ++r)
            o4[t + 512*r] = make_float4(0.f,0.f,0.f,0.f);
        return;
    }

    __shared__ float s_Yq[512][17];
    __shared__ float s_wq[512];
    __shared__ float s_part[256];
    __shared__ float red[256];
    __shared__ float s_scale;

    const int p = blockIdx.x;
    const int l1 = P_L1[p], l2 = P_L2[p], l3 = P_L3[p];
    const int d2 = 2*l2+1, d3 = 2*l3+1;
    const int csize = (2*l1+1)*d2*d3;
    const double step = 2.0*3.14159265358979323846/32.0;

    // weight transpose (independent of quadrature)
#pragma unroll
    for (int r = 0; r < 2; ++r) {
        const int idx = t + 512*r;
        const int w = idx >> 5, u = idx & 31;
        const float vw = ww[p*1024 + u*32 + w];
        const float vb = wb[p*1024 + u*32 + w];
        const unsigned short hw = bf16rne(vw);
        const unsigned short hb = bf16rne(vb);
        const int o = p*1024 + w*32 + u;
        Awhi[o] = hw;  Awlo[o] = bf16rne(vw - bf16f(hw));
        Abhi[o] = hb;  Ablo[o] = bf16rne(vb - bf16f(hb));
    }

    // phase A: one quadrature point per thread
    {
        const int q = t, iu = q >> 5, ip = q & 31;
        const double u = GLX[iu];
        const double st = sqrt(fmax(1.0 - u*u, 0.0));
        double Y[16];
        sh_f64(st*COSP[ip], st*SINP[ip], u, Y);
#pragma unroll
        for (int i = 0; i < 16; ++i) s_Yq[q][i] = (float)Y[i];
        s_wq[q] = (float)(GLW[iu] * step);
    }
    __syncthreads();

    // phase B: 4 threads per entry, 128 interleaved points each, shuffle-reduce
    const int entry0 = t >> 2, sub = t & 3;
#pragma unroll
    for (int pass = 0; pass < 2; ++pass) {
        const int entry = entry0 + pass*128;
        float acc = 0.f;
        if (entry < csize) {
            const int i = entry/(d2*d3); const int r = entry - i*(d2*d3);
            const int j = r/d3; const int k = r - j*d3;
            const int ai = l1*l1+i, bi = l2*l2+j, ci = l3*l3+k;
#pragma unroll 4
            for (int it = 0; it < 128; ++it) {
                const int q = it*4 + sub;
                acc = fmaf(s_wq[q] * s_Yq[q][ai] * s_Yq[q][bi], s_Yq[q][ci], acc);
            }
        }
        acc += __shfl_xor(acc, 1);
        acc += __shfl_xor(acc, 2);
        if (sub == 0 && entry < csize) s_part[entry] = acc;
    }
    __syncthreads();

    if (t < 256) { const float v = (t < csize) ? s_part[t] : 0.f; red[t] = v*v; }
    __syncthreads();
    for (int s = 128; s > 0; s >>= 1) {
        if (t < s) red[t] += red[t+s];
        __syncthreads();
    }
    if (t == 0) {
        const float pw = sqrtf((float)(2*l3+1) / ((float)CNT_L3[l3] * (float)HIDDEN));
        s_scale = pw / sqrtf(red[0]);
    }
    __syncthreads();
    if (t < csize) g_w3j[C_OFF[p] + t] = s_part[t] * s_scale;
}

// ---- tmp compute + B-operand staging (2 edges x 32 u-lanes per wave) ----
template<int D1>
__device__ inline void tmp_stage(int lane, int d3,
                                 const float* __restrict__ xrow, // nf + src[el]*FEAT + xoff
                                 const float* __restrict__ zw,   // wave's s_zp region
                                 unsigned short* __restrict__ bh,
                                 unsigned short* __restrict__ bl) {
    const int el = lane >> 5, u = lane & 31;
    const float* xg = xrow + u*D1;
    float xv[D1];
#pragma unroll
    for (int i = 0; i < D1; ++i) xv[i] = xg[i];
    const float* zr = zw + el*49;
    for (int k = 0; k < d3; ++k) {
        float t0 = 0.f;
#pragma unroll
        for (int i = 0; i < D1; ++i) t0 = fmaf(xv[i], zr[i*d3 + k], t0);
        const int c = el*d3 + k;
        const unsigned short h0 = bf16rne(t0);
        bh[c*40 + u] = h0;
        bl[c*40 + u] = bf16rne(t0 - bf16f(h0));
    }
}

// ---- main: 2 waves/block, 2 edges/wave, wave-synchronous ----
__global__ __launch_bounds__(BLK) void edge_kernel(
    const float* __restrict__ nf,   // (N_NODES, FEAT)
    const int*   __restrict__ eidx, // (2, N_EDGES)
    const float* __restrict__ ev,   // (N_EDGES, 3)
    const float* __restrict__ w3j,  // (1875,)
    const unsigned short* __restrict__ Awhi,
    const unsigned short* __restrict__ Awlo,
    const unsigned short* __restrict__ Abhi,
    const unsigned short* __restrict__ Ablo,
    float*       __restrict__ out)  // (N_NODES, FEAT) pre-zeroed
{
    __shared__ float s_zp[2][2*49];
    __shared__ float s_Y[2][32];
    __shared__ float s_len[2][2];
    __shared__ int   s_src[2][2];
    __shared__ int   s_dst[2][2];
    __shared__ __align__(16) unsigned short s_Bhi[2][640];  // [col(16)][u(32)+pad8]
    __shared__ __align__(16) unsigned short s_Blo[2][640];
    __shared__ float s_msg[2][2*FEAT];   // 4 KB per wave

    const int t    = threadIdx.x;
    const int wave = t >> 6;
    const int lane = t & 63;
    const int ln   = lane & 15;    // n / m-low
    const int lq   = lane >> 4;    // quad
    const int e0   = blockIdx.x * EB + wave*2;

    // per-wave prologue: lanes 0-1 handle this wave's 2 edges
    if (lane < 2) {
        const int e = e0 + lane;
        s_src[wave][lane] = eidx[e];
        s_dst[wave][lane] = eidx[N_EDGES + e];
        const float x = ev[e*3+0], y = ev[e*3+1], z = ev[e*3+2];
        const float len = sqrtf(x*x + y*y + z*z);
        const float lc = fmaxf(len, 1e-8f);
        s_len[wave][lane] = lc;
        float Yl[16];
        sh_f32(x/lc, y/lc, z/lc, Yl);
#pragma unroll
        for (int i = 0; i < 16; ++i) s_Y[wave][lane*16+i] = Yl[i];
    }
    WAVE_SYNC();

    // this lane's node-feature row (el = lane>>5 fixed)
    const float* xrow = nf + (size_t)s_src[wave][lane >> 5]*FEAT;

    for (int g = 0; g < 4; ++g) {
        const int d3g = 2*g + 1;
        f32x4 Cw[2], Cb[2];
#pragma unroll
        for (int mt = 0; mt < 2; ++mt) {
            Cw[mt] = (f32x4){0.f,0.f,0.f,0.f};
            Cb[mt] = (f32x4){0.f,0.f,0.f,0.f};
        }

        for (int pi = L3START[g]; pi < L3START[g+1]; ++pi) {
            const int p  = L3PATHS[pi];
            const int l1 = P_L1[p], l2 = P_L2[p];
            const int d1 = 2*l1+1, d2 = 2*l2+1;
            const int zc = d1*d3g;

            // z[el][i][k] = sum_j Y[el][l2^2+j] * C[i][j][k]   (C via L1)
            const float* Cp0 = w3j + C_OFF[p];
            for (int idx = lane; idx < 2*zc; idx += 64) {
                const int el = idx / zc, r = idx - el*zc;
                const int i = r / d3g, k = r - i*d3g;
                const float* Cp = Cp0 + i*d2*d3g + k;
                const float* Yp = &s_Y[wave][el*16 + l2*l2];
                float acc = 0.f;
                for (int j = 0; j < d2; ++j) acc = fmaf(Yp[j], Cp[j*d3g], acc);
                s_zp[wave][el*49 + r] = acc;
            }
            WAVE_SYNC();

            // tmp + stage B-fragments (bf16 hi/lo) into wave-private LDS
            const int xoff = HIDDEN*l1*l1;
            switch (l1) {
                case 0: tmp_stage<1>(lane, d3g, xrow+xoff, s_zp[wave], s_Bhi[wave], s_Blo[wave]); break;
                case 1: tmp_stage<3>(lane, d3g, xrow+xoff, s_zp[wave], s_Bhi[wave], s_Blo[wave]); break;
                case 2: tmp_stage<5>(lane, d3g, xrow+xoff, s_zp[wave], s_Bhi[wave], s_Blo[wave]); break;
                default: tmp_stage<7>(lane, d3g, xrow+xoff, s_zp[wave], s_Bhi[wave], s_Blo[wave]); break;
            }
            WAVE_SYNC();

            // GEMM: D[w][c] += W^T[w][u] * tmp[u][c], K=32, 3-pass hi/lo split
            bf16x8 awh[2], awl[2], abh[2], abl[2];
#pragma unroll
            for (int mt = 0; mt < 2; ++mt) {
                const int m = mt*16 + ln;
                const int ao = p*1024 + m*32 + lq*8;
                awh[mt] = *(const bf16x8*)(Awhi + ao);
                awl[mt] = *(const bf16x8*)(Awlo + ao);
                abh[mt] = *(const bf16x8*)(Abhi + ao);
                abl[mt] = *(const bf16x8*)(Ablo + ao);
            }
            const int bo = ln*40 + lq*8;
            const bf16x8 bh = *(const bf16x8*)(s_Bhi[wave] + bo);
            const bf16x8 bl = *(const bf16x8*)(s_Blo[wave] + bo);
#pragma unroll
            for (int mt = 0; mt < 2; ++mt) {
                Cw[mt] = __builtin_amdgcn_mfma_f32_16x16x32_bf16(awh[mt], bh, Cw[mt], 0, 0, 0);
                Cw[mt] = __builtin_amdgcn_mfma_f32_16x16x32_bf16(awh[mt], bl, Cw[mt], 0, 0, 0);
                Cw[mt] = __builtin_amdgcn_mfma_f32_16x16x32_bf16(awl[mt], bh, Cw[mt], 0, 0, 0);
                Cb[mt] = __builtin_amdgcn_mfma_f32_16x16x32_bf16(abh[mt], bh, Cb[mt], 0, 0, 0);
                Cb[mt] = __builtin_amdgcn_mfma_f32_16x16x32_bf16(abh[mt], bl, Cb[mt], 0, 0, 0);
                Cb[mt] = __builtin_amdgcn_mfma_f32_16x16x32_bf16(abl[mt], bh, Cb[mt], 0, 0, 0);
            }
            WAVE_SYNC();  // B reads done before next path's tmp_stage overwrites
        }

        // group epilogue: msg = len*Cw + Cb  (wave-private, unique owners)
        {
            const int c = ln;
            if (c < 2*d3g) {
                const int el = c/d3g;
                const int k  = c - el*d3g;
                const float len = s_len[wave][el];
                float* mp = &s_msg[wave][el*FEAT + OFF3[g] + k];
#pragma unroll
                for (int mt = 0; mt < 2; ++mt) {
#pragma unroll
                    for (int r = 0; r < 4; ++r) {
                        const int w = mt*16 + lq*4 + r;
                        mp[w*d3g] = fmaf(len, Cw[mt][r], Cb[mt][r]);
                    }
                }
            }
        }
    }
    WAVE_SYNC();

    // wave-local coalesced scatter: 2 edges x 512, 16 atomics/lane
    for (int i = lane; i < 2*FEAT; i += 64) {
        const int el = i >> 9, m = i & 511;
        atomicAdd(&out[(size_t)s_dst[wave][el]*FEAT + m], s_msg[wave][i]);
    }
}

extern "C" void kernel_launch(void* const* d_in, const int* in_sizes, int n_in,
                              void* d_out, int out_size, void* d_ws, size_t ws_size,
                              hipStream_t stream) {
    const float* nf   = (const float*)d_in[0];
    const int*   eidx = (const int*)  d_in[1];
    const float* ev   = (const float*)d_in[2];
    const float* ww   = (const float*)d_in[3];
    const float* wb   = (const float*)d_in[4];
    float* out = (float*)d_out;

    float* w3j = (float*)d_ws;                                   // 7500 B
    unsigned short* Awhi = (unsigned short*)((char*)d_ws + 16384);
    unsigned short* Awlo = Awhi + N_PATHS*1024;
    unsigned short* Abhi = Awlo + N_PATHS*1024;
    unsigned short* Ablo = Abhi + N_PATHS*1024;                  // ends at 204800 B

    w3j_setup_kernel<<<N_PATHS + ZERO_BLOCKS, 512, 0, stream>>>(
        ww, wb, w3j, Awhi, Awlo, Abhi, Ablo, out);
    edge_kernel<<<N_EDGES/EB, BLK, 0, stream>>>(nf, eidx, ev, w3j, Awhi, Awlo, Abhi, Ablo, out);
}

// Round 10
// 141.811 us; speedup vs baseline: 1.1089x; 1.1089x over previous
//
#include <hip/hip_runtime.h>
#include <math.h>

#define N_PATHS 23
#define HIDDEN  32
#define N_NODES 4096
#define N_EDGES 8192
#define FEAT    512
#define BLK     128   // 2 waves; 2 edges per wave
#define ZERO_BLOCKS 256

// wave-local LDS phase separator (all prior DS ops complete)
#define WAVE_SYNC() asm volatile("s_waitcnt lgkmcnt(0)" ::: "memory")

typedef __attribute__((ext_vector_type(8))) short bf16x8;
typedef __attribute__((ext_vector_type(4))) float f32x4;

// ---- compile-time path metadata (PATHS enumeration: l1 outer, l2, l3) ----
constexpr int cL1[N_PATHS] = {0,0,0,0, 1,1,1,1,1,1, 2,2,2,2,2,2,2, 3,3,3,3,3,3};
constexpr int cL2[N_PATHS] = {0,1,2,3, 0,1,1,2,2,3, 0,1,1,2,2,3,3, 0,1,2,2,3,3};
constexpr int cL3[N_PATHS] = {0,1,2,3, 1,0,2,1,3,2, 2,1,3,0,2,1,3, 3,2,1,3,0,2};
constexpr int cCOFF[N_PATHS]= {0,1,10,35,84,93,102,147,192,297,402,427,472,577,602,727,832,1077,1126,1231,1336,1581,1630};
constexpr int cL3P[N_PATHS] = {0,5,13,21, 1,4,7,11,15,19, 2,6,9,10,14,18,22, 3,8,12,16,17,20};
constexpr int cL3S[5] = {0,4,10,17,23};
constexpr int cOFF3[4] = {0,32,128,288};
__device__ const int CNT_L3[4] = {4,6,7,6};
__device__ const int D_L3[N_PATHS] = {0,1,2,3, 1,0,2,1,3,2, 2,1,3,0,2,1,3, 3,2,1,3,0,2};

// ---- 8-point Gauss-Legendre nodes/weights (128-pt rule: exact for degree<=9 SH triple products) ----
__device__ const double GLX8[8] = {
    -0.96028985649753623168, -0.79666647741362673959, -0.52553240991632898582, -0.18343464249564980494,
     0.18343464249564980494,  0.52553240991632898582,  0.79666647741362673959,  0.96028985649753623168};
__device__ const double GLW8[8] = {
     0.10122853629037625915,  0.22238103445337447054,  0.31370664587788728734,  0.36268378337836198297,
     0.36268378337836198297,  0.31370664587788728734,  0.22238103445337447054,  0.10122853629037625915};
// cos/sin(k*pi/8), k=0..15 — exact literals
__device__ const double COSP16[16] = {
  1.0,                     0.92387953251128675613,  0.70710678118654752440,  0.38268343236508977173,
  0.0,                    -0.38268343236508977173, -0.70710678118654752440, -0.92387953251128675613,
 -1.0,                    -0.92387953251128675613, -0.70710678118654752440, -0.38268343236508977173,
  0.0,                     0.38268343236508977173,  0.70710678118654752440,  0.92387953251128675613};
__device__ const double SINP16[16] = {
  0.0,                     0.38268343236508977173,  0.70710678118654752440,  0.92387953251128675613,
  1.0,                     0.92387953251128675613,  0.70710678118654752440,  0.38268343236508977173,
  0.0,                    -0.38268343236508977173, -0.70710678118654752440, -0.92387953251128675613,
 -1.0,                    -0.92387953251128675613, -0.70710678118654752440, -0.38268343236508977173};

__device__ inline void sh_f64(double x, double y, double z, double* Y) {
    const double s3 = 1.7320508075688772935, s5 = 2.2360679774997896964,
                 s7 = 2.6457513110645905905, s15 = 3.8729833462074168852;
    const double c58 = 0.79056941504209483300, c38 = 0.61237243569579452455;
    Y[0] = 1.0;
    Y[1] = s3*x;  Y[2] = s3*y;  Y[3] = s3*z;
    Y[4] = s5*s3*x*z;  Y[5] = s5*s3*x*y;
    Y[6] = s5*(y*y - 0.5*(x*x + z*z));
    Y[7] = s5*s3*y*z;  Y[8] = s5*(s3/2.0)*(z*z - x*x);
    Y[9] = s7*c58*x*(3.0*z*z - x*x);
    Y[10]= s7*s15*x*y*z;
    Y[11]= s7*c38*x*(5.0*y*y - 1.0);
    Y[12]= s7*0.5*y*(5.0*y*y - 3.0);
    Y[13]= s7*c38*z*(5.0*y*y - 1.0);
    Y[14]= s7*(s15/2.0)*y*(z*z - x*x);
    Y[15]= s7*c58*z*(z*z - 3.0*x*x);
}

__device__ inline void sh_f32(float x, float y, float z, float* Y) {
    const float s3 = 1.73205080757f, s5 = 2.23606797750f, s7 = 2.64575131106f, s15 = 3.87298334621f;
    const float c58 = 0.79056941504f, c38 = 0.61237243570f;
    Y[0] = 1.0f;
    Y[1] = s3*x;  Y[2] = s3*y;  Y[3] = s3*z;
    Y[4] = s15*x*z;  Y[5] = s15*x*y;
    Y[6] = s5*(y*y - 0.5f*(x*x + z*z));
    Y[7] = s15*y*z;  Y[8] = s5*(s3*0.5f)*(z*z - x*x);
    Y[9] = s7*c58*x*(3.0f*z*z - x*x);
    Y[10]= s7*s15*x*y*z;
    Y[11]= s7*c38*x*(5.0f*y*y - 1.0f);
    Y[12]= s7*0.5f*y*(5.0f*y*y - 3.0f);
    Y[13]= s7*c38*z*(5.0f*y*y - 1.0f);
    Y[14]= s7*(s15*0.5f)*y*(z*z - x*x);
    Y[15]= s7*c58*z*(z*z - 3.0f*x*x);
}

__device__ inline unsigned short bf16rne(float x) {
    unsigned int u = __float_as_uint(x);
    unsigned int r = (u + 0x7FFFu + ((u >> 16) & 1u)) >> 16;
    return (unsigned short)r;
}
__device__ inline float bf16f(unsigned short h) {
    return __uint_as_float(((unsigned int)h) << 16);
}

// ---- setup: W3J tables (128-pt quadrature) + weight transpose + output zeroing ----
__global__ __launch_bounds__(512) void w3j_setup_kernel(
    const float* __restrict__ ww, const float* __restrict__ wb,
    float* __restrict__ g_w3j,
    unsigned short* __restrict__ Awhi, unsigned short* __restrict__ Awlo,
    unsigned short* __restrict__ Abhi, unsigned short* __restrict__ Ablo,
    float* __restrict__ out) {
    const int t = threadIdx.x;

    if (blockIdx.x >= N_PATHS) {   // zero-blocks
        const int b = blockIdx.x - N_PATHS;
        float4* o4 = (float4*)(out + (size_t)b * (N_NODES*FEAT/ZERO_BLOCKS));
#pragma unroll
        for (int r = 0; r < 4; ++r)
            o4[t + 512*r] = make_float4(0.f,0.f,0.f,0.f);
        return;
    }

    __shared__ float s_Yq[128][17];
    __shared__ float s_wq[128];
    __shared__ float s_part[256];
    __shared__ float red[256];
    __shared__ float s_scale;

    const int p = blockIdx.x;
    const int l1 = cL1[p], l2 = cL2[p];
    const int l3 = D_L3[p];
    const int d2 = 2*l2+1, d3 = 2*l3+1;
    const int csize = (2*l1+1)*d2*d3;
    const double step = 2.0*3.14159265358979323846/16.0;

    // weight transpose to A-layout [p][w][u], bf16 hi/lo split
#pragma unroll
    for (int r = 0; r < 2; ++r) {
        const int idx = t + 512*r;
        const int w = idx >> 5, u = idx & 31;
        const float vw = ww[p*1024 + u*32 + w];
        const float vb = wb[p*1024 + u*32 + w];
        const unsigned short hw = bf16rne(vw);
        const unsigned short hb = bf16rne(vb);
        const int o = p*1024 + w*32 + u;
        Awhi[o] = hw;  Awlo[o] = bf16rne(vw - bf16f(hw));
        Abhi[o] = hb;  Ablo[o] = bf16rne(vb - bf16f(hb));
    }

    // phase A: one quadrature point per thread (first 128 threads)
    if (t < 128) {
        const int iu = t >> 4, ip = t & 15;
        const double u = GLX8[iu];
        const double st = sqrt(fmax(1.0 - u*u, 0.0));
        double Y[16];
        sh_f64(st*COSP16[ip], st*SINP16[ip], u, Y);
#pragma unroll
        for (int i = 0; i < 16; ++i) s_Yq[t][i] = (float)Y[i];
        s_wq[t] = (float)(GLW8[iu] * step);
    }
    __syncthreads();

    // phase B: 4 threads/entry, 32 interleaved points each, shuffle-reduce
    const int entry0 = t >> 2, sub = t & 3;
#pragma unroll
    for (int pass = 0; pass < 2; ++pass) {
        const int entry = entry0 + pass*128;
        float acc = 0.f;
        if (entry < csize) {
            const int i = entry/(d2*d3); const int r = entry - i*(d2*d3);
            const int j = r/d3; const int k = r - j*d3;
            const int ai = l1*l1+i, bi = l2*l2+j, ci = l3*l3+k;
#pragma unroll 4
            for (int it = 0; it < 32; ++it) {
                const int q = it*4 + sub;
                acc = fmaf(s_wq[q] * s_Yq[q][ai] * s_Yq[q][bi], s_Yq[q][ci], acc);
            }
        }
        acc += __shfl_xor(acc, 1);
        acc += __shfl_xor(acc, 2);
        if (sub == 0 && entry < csize) s_part[entry] = acc;
    }
    __syncthreads();

    if (t < 256) { const float v = (t < csize) ? s_part[t] : 0.f; red[t] = v*v; }
    __syncthreads();
    for (int s = 128; s > 0; s >>= 1) {
        if (t < s) red[t] += red[t+s];
        __syncthreads();
    }
    if (t == 0) {
        const float pw = sqrtf((float)(2*l3+1) / ((float)CNT_L3[l3] * (float)HIDDEN));
        s_scale = pw / sqrtf(red[0]);
    }
    __syncthreads();
    if (t < csize) g_w3j[cCOFF[p] + t] = s_part[t] * s_scale;
}

// ---- one fully-unrolled path: z -> tmp/stage -> MFMA (all indices compile-time) ----
template<int G, int P>
__device__ __forceinline__ void do_path(
    int lane, int u, int el, int bvaddr, int avaddr,
    const float (&xr)[16],
    const float* __restrict__ w3j,
    const unsigned short* __restrict__ Awhi, const unsigned short* __restrict__ Awlo,
    const unsigned short* __restrict__ Abhi, const unsigned short* __restrict__ Ablo,
    const float* sY, float* sz,
    unsigned short* sbh, unsigned short* sbl,
    f32x4 (&Cw)[2], f32x4 (&Cb)[2])
{
    constexpr int l1 = cL1[P], l2 = cL2[P];
    constexpr int d1 = 2*l1+1, d2 = 2*l2+1, d3 = 2*G+1;
    constexpr int zc = d1*d3;
    constexpr int xo = l1*l1;

    // z[el][i][k] = sum_j Y[el][l2^2+j] * C[i][j][k]
    // 2*zc can exceed 64 (up to 98) -> compile-time-unrolled 2-iteration loop
#pragma unroll
    for (int base = 0; base < 2*zc; base += 64) {
        const int idx = base + lane;
        if (idx < 2*zc) {
            const int elz = (idx >= zc) ? 1 : 0;
            const int r = idx - elz*zc;
            const int i = r / d3, k = r - i*d3;   // const-div by d3
            const float* Cp = w3j + cCOFF[P] + i*(d2*d3) + k;
            const float* Yp = sY + elz*16 + l2*l2;
            float acc = 0.f;
#pragma unroll
            for (int j = 0; j < d2; ++j) acc = fmaf(Yp[j], Cp[j*d3], acc);
            sz[elz*49 + r] = acc;
        }
    }
    WAVE_SYNC();

    // tmp[u][k] = sum_i x[u,i]*z[i,k]; chop-split bf16 hi/lo; immediate-offset stores
    {
        const float* zr = sz + el*49;
        unsigned short* bh = sbh + el*(d3*40) + u;
        unsigned short* bl = sbl + el*(d3*40) + u;
#pragma unroll
        for (int k = 0; k < d3; ++k) {
            float tv = 0.f;
#pragma unroll
            for (int i = 0; i < d1; ++i) tv = fmaf(xr[xo+i], zr[i*d3+k], tv);
            const unsigned int tb = __float_as_uint(tv);
            const float lof = tv - __uint_as_float(tb & 0xFFFF0000u);  // exact residual
            bh[k*40] = (unsigned short)(tb >> 16);
            bl[k*40] = (unsigned short)(__float_as_uint(lof) >> 16);
        }
    }
    WAVE_SYNC();

    // A loads (L2-resident, compile-time bases) + 6 MFMA (3-pass hi/lo x {w,b})
    const unsigned short* pwh = Awhi + P*1024;
    const unsigned short* pwl = Awlo + P*1024;
    const unsigned short* pbh = Abhi + P*1024;
    const unsigned short* pbl = Ablo + P*1024;
    bf16x8 awh[2], awl[2], abh[2], abl[2];
#pragma unroll
    for (int mt = 0; mt < 2; ++mt) {
        awh[mt] = *(const bf16x8*)(pwh + mt*512 + avaddr);
        awl[mt] = *(const bf16x8*)(pwl + mt*512 + avaddr);
        abh[mt] = *(const bf16x8*)(pbh + mt*512 + avaddr);
        abl[mt] = *(const bf16x8*)(pbl + mt*512 + avaddr);
    }
    const bf16x8 bh = *(const bf16x8*)(sbh + bvaddr);
    const bf16x8 bl = *(const bf16x8*)(sbl + bvaddr);
#pragma unroll
    for (int mt = 0; mt < 2; ++mt) {
        Cw[mt] = __builtin_amdgcn_mfma_f32_16x16x32_bf16(awh[mt], bh, Cw[mt], 0, 0, 0);
        Cw[mt] = __builtin_amdgcn_mfma_f32_16x16x32_bf16(awh[mt], bl, Cw[mt], 0, 0, 0);
        Cw[mt] = __builtin_amdgcn_mfma_f32_16x16x32_bf16(awl[mt], bh, Cw[mt], 0, 0, 0);
        Cb[mt] = __builtin_amdgcn_mfma_f32_16x16x32_bf16(abh[mt], bh, Cb[mt], 0, 0, 0);
        Cb[mt] = __builtin_amdgcn_mfma_f32_16x16x32_bf16(abh[mt], bl, Cb[mt], 0, 0, 0);
        Cb[mt] = __builtin_amdgcn_mfma_f32_16x16x32_bf16(abl[mt], bh, Cb[mt], 0, 0, 0);
    }
    WAVE_SYNC();  // B reads done before next path's stage overwrites
}

template<int G>
__device__ __forceinline__ void do_group(
    int lane, int u, int el, int ln, int lq, int bvaddr, int avaddr,
    const float (&xr)[16],
    const float* __restrict__ w3j,
    const unsigned short* __restrict__ Awhi, const unsigned short* __restrict__ Awlo,
    const unsigned short* __restrict__ Abhi, const unsigned short* __restrict__ Ablo,
    const float* sY, float* sz,
    unsigned short* sbh, unsigned short* sbl,
    const float* slen, float* smsg)
{
    constexpr int d3 = 2*G+1;
    constexpr int s = cL3S[G];
    constexpr int n = cL3S[G+1] - cL3S[G];
    f32x4 Cw[2], Cb[2];
#pragma unroll
    for (int mt = 0; mt < 2; ++mt) {
        Cw[mt] = (f32x4){0.f,0.f,0.f,0.f};
        Cb[mt] = (f32x4){0.f,0.f,0.f,0.f};
    }

    do_path<G, cL3P[s+0]>(lane,u,el,bvaddr,avaddr,xr,w3j,Awhi,Awlo,Abhi,Ablo,sY,sz,sbh,sbl,Cw,Cb);
    do_path<G, cL3P[s+1]>(lane,u,el,bvaddr,avaddr,xr,w3j,Awhi,Awlo,Abhi,Ablo,sY,sz,sbh,sbl,Cw,Cb);
    do_path<G, cL3P[s+2]>(lane,u,el,bvaddr,avaddr,xr,w3j,Awhi,Awlo,Abhi,Ablo,sY,sz,sbh,sbl,Cw,Cb);
    do_path<G, cL3P[s+3]>(lane,u,el,bvaddr,avaddr,xr,w3j,Awhi,Awlo,Abhi,Ablo,sY,sz,sbh,sbl,Cw,Cb);
    if constexpr (n > 4)
        do_path<G, cL3P[s+4]>(lane,u,el,bvaddr,avaddr,xr,w3j,Awhi,Awlo,Abhi,Ablo,sY,sz,sbh,sbl,Cw,Cb);
    if constexpr (n > 5)
        do_path<G, cL3P[s+5]>(lane,u,el,bvaddr,avaddr,xr,w3j,Awhi,Awlo,Abhi,Ablo,sY,sz,sbh,sbl,Cw,Cb);
    if constexpr (n > 6)
        do_path<G, cL3P[s+6]>(lane,u,el,bvaddr,avaddr,xr,w3j,Awhi,Awlo,Abhi,Ablo,sY,sz,sbh,sbl,Cw,Cb);

    // epilogue: msg = len*Cw + Cb (unique owners; const d3)
    if (ln < 2*d3) {
        const int elc = ln / d3, k = ln - elc*d3;
        const float len = slen[elc];
        float* mp = smsg + elc*FEAT + cOFF3[G] + k;
#pragma unroll
        for (int mt = 0; mt < 2; ++mt)
#pragma unroll
            for (int r = 0; r < 4; ++r)
                mp[(mt*16 + lq*4 + r)*d3] = fmaf(len, Cw[mt][r], Cb[mt][r]);
    }
}

// ---- main: 2 waves/block, 2 edges/wave, fully unrolled ----
__global__ __launch_bounds__(BLK, 4) void edge_kernel(
    const float* __restrict__ nf,
    const int*   __restrict__ eidx,
    const float* __restrict__ ev,
    const float* __restrict__ w3j,
    const unsigned short* __restrict__ Awhi,
    const unsigned short* __restrict__ Awlo,
    const unsigned short* __restrict__ Abhi,
    const unsigned short* __restrict__ Ablo,
    float*       __restrict__ out)
{
    __shared__ float s_zp[2][2*49];
    __shared__ float s_Y[2][32];
    __shared__ float s_len[2][2];
    __shared__ int   s_src[2][2];
    __shared__ int   s_dst[2][2];
    __shared__ __align__(16) unsigned short s_Bhi[2][640];
    __shared__ __align__(16) unsigned short s_Blo[2][640];
    __shared__ float s_msg[2][2*FEAT];

    const int t    = threadIdx.x;
    const int wave = t >> 6;
    const int lane = t & 63;
    const int ln   = lane & 15;
    const int lq   = lane >> 4;
    const int u    = lane & 31;
    const int el   = lane >> 5;
    const int e0   = blockIdx.x * 4 + wave*2;
    const int bvaddr = ln*40 + lq*8;
    const int avaddr = ln*32 + lq*8;

    if (lane < 2) {
        const int e = e0 + lane;
        s_src[wave][lane] = eidx[e];
        s_dst[wave][lane] = eidx[N_EDGES + e];
        const float x = ev[e*3+0], y = ev[e*3+1], z = ev[e*3+2];
        const float len = sqrtf(x*x + y*y + z*z);
        const float lc = fmaxf(len, 1e-8f);
        s_len[wave][lane] = lc;
        float Yl[16];
        sh_f32(x/lc, y/lc, z/lc, Yl);
#pragma unroll
        for (int i = 0; i < 16; ++i) s_Y[wave][lane*16+i] = Yl[i];
    }
    WAVE_SYNC();

    // preload this lane's 16 x-values (all l1 chunks) into registers
    float xr[16];
    {
        const float* xrow = nf + (size_t)s_src[wave][el]*FEAT;
        xr[0] = xrow[u];
#pragma unroll
        for (int i = 0; i < 3; ++i) xr[1+i] = xrow[32 + u*3 + i];
#pragma unroll
        for (int i = 0; i < 5; ++i) xr[4+i] = xrow[128 + u*5 + i];
#pragma unroll
        for (int i = 0; i < 7; ++i) xr[9+i] = xrow[288 + u*7 + i];
    }

    do_group<0>(lane,u,el,ln,lq,bvaddr,avaddr,xr,w3j,Awhi,Awlo,Abhi,Ablo,
                s_Y[wave], s_zp[wave], s_Bhi[wave], s_Blo[wave], s_len[wave], s_msg[wave]);
    do_group<1>(lane,u,el,ln,lq,bvaddr,avaddr,xr,w3j,Awhi,Awlo,Abhi,Ablo,
                s_Y[wave], s_zp[wave], s_Bhi[wave], s_Blo[wave], s_len[wave], s_msg[wave]);
    do_group<2>(lane,u,el,ln,lq,bvaddr,avaddr,xr,w3j,Awhi,Awlo,Abhi,Ablo,
                s_Y[wave], s_zp[wave], s_Bhi[wave], s_Blo[wave], s_len[wave], s_msg[wave]);
    do_group<3>(lane,u,el,ln,lq,bvaddr,avaddr,xr,w3j,Awhi,Awlo,Abhi,Ablo,
                s_Y[wave], s_zp[wave], s_Bhi[wave], s_Blo[wave], s_len[wave], s_msg[wave]);
    WAVE_SYNC();

    // wave-local coalesced scatter
    for (int i = lane; i < 2*FEAT; i += 64) {
        const int elc = i >> 9, m = i & 511;
        atomicAdd(&out[(size_t)s_dst[wave][elc]*FEAT + m], s_msg[wave][i]);
    }
}

extern "C" void kernel_launch(void* const* d_in, const int* in_sizes, int n_in,
                              void* d_out, int out_size, void* d_ws, size_t ws_size,
                              hipStream_t stream) {
    const float* nf   = (const float*)d_in[0];
    const int*   eidx = (const int*)  d_in[1];
    const float* ev   = (const float*)d_in[2];
    const float* ww   = (const float*)d_in[3];
    const float* wb   = (const float*)d_in[4];
    float* out = (float*)d_out;

    float* w3j = (float*)d_ws;                                   // 7500 B
    unsigned short* Awhi = (unsigned short*)((char*)d_ws + 16384);
    unsigned short* Awlo = Awhi + N_PATHS*1024;
    unsigned short* Abhi = Awlo + N_PATHS*1024;
    unsigned short* Ablo = Abhi + N_PATHS*1024;                  // ends at 204800 B

    w3j_setup_kernel<<<N_PATHS + ZERO_BLOCKS, 512, 0, stream>>>(
        ww, wb, w3j, Awhi, Awlo, Abhi, Ablo, out);
    edge_kernel<<<N_EDGES/4, BLK, 0, stream>>>(nf, eidx, ev, w3j, Awhi, Awlo, Abhi, Ablo, out);
}

// Round 11
// 121.372 us; speedup vs baseline: 1.2957x; 1.1684x over previous
//
#include <hip/hip_runtime.h>
#include <math.h>

#define N_PATHS 23
#define HIDDEN  32
#define N_NODES 4096
#define N_EDGES 8192
#define FEAT    512
#define BLK     128   // 2 waves; 4 edges per wave
#define ZERO_BLOCKS 256

// wave-local LDS phase separator (all prior DS ops complete)
#define WAVE_SYNC() asm volatile("s_waitcnt lgkmcnt(0)" ::: "memory")

typedef __attribute__((ext_vector_type(8)))  short bf16x8;
typedef __attribute__((ext_vector_type(16))) float f32x16;

// ---- compile-time path metadata (PATHS enumeration: l1 outer, l2, l3) ----
constexpr int cL1[N_PATHS] = {0,0,0,0, 1,1,1,1,1,1, 2,2,2,2,2,2,2, 3,3,3,3,3,3};
constexpr int cL2[N_PATHS] = {0,1,2,3, 0,1,1,2,2,3, 0,1,1,2,2,3,3, 0,1,2,2,3,3};
constexpr int cCOFF[N_PATHS]= {0,1,10,35,84,93,102,147,192,297,402,427,472,577,602,727,832,1077,1126,1231,1336,1581,1630};
constexpr int cL3P[N_PATHS] = {0,5,13,21, 1,4,7,11,15,19, 2,6,9,10,14,18,22, 3,8,12,16,17,20};
constexpr int cL3S[5] = {0,4,10,17,23};
constexpr int cOFF3[4] = {0,32,128,288};
__device__ const int CNT_L3[4] = {4,6,7,6};
__device__ const int D_L3[N_PATHS] = {0,1,2,3, 1,0,2,1,3,2, 2,1,3,0,2,1,3, 3,2,1,3,0,2};

// ---- 8-point Gauss-Legendre nodes/weights (128-pt rule: exact for degree<=9 SH triple products) ----
__device__ const double GLX8[8] = {
    -0.96028985649753623168, -0.79666647741362673959, -0.52553240991632898582, -0.18343464249564980494,
     0.18343464249564980494,  0.52553240991632898582,  0.79666647741362673959,  0.96028985649753623168};
__device__ const double GLW8[8] = {
     0.10122853629037625915,  0.22238103445337447054,  0.31370664587788728734,  0.36268378337836198297,
     0.36268378337836198297,  0.31370664587788728734,  0.22238103445337447054,  0.10122853629037625915};
// cos/sin(k*pi/8), k=0..15 — exact literals
__device__ const double COSP16[16] = {
  1.0,                     0.92387953251128675613,  0.70710678118654752440,  0.38268343236508977173,
  0.0,                    -0.38268343236508977173, -0.70710678118654752440, -0.92387953251128675613,
 -1.0,                    -0.92387953251128675613, -0.70710678118654752440, -0.38268343236508977173,
  0.0,                     0.38268343236508977173,  0.70710678118654752440,  0.92387953251128675613};
__device__ const double SINP16[16] = {
  0.0,                     0.38268343236508977173,  0.70710678118654752440,  0.92387953251128675613,
  1.0,                     0.92387953251128675613,  0.70710678118654752440,  0.38268343236508977173,
  0.0,                    -0.38268343236508977173, -0.70710678118654752440, -0.92387953251128675613,
 -1.0,                    -0.92387953251128675613, -0.70710678118654752440, -0.38268343236508977173};

__device__ inline void sh_f64(double x, double y, double z, double* Y) {
    const double s3 = 1.7320508075688772935, s5 = 2.2360679774997896964,
                 s7 = 2.6457513110645905905, s15 = 3.8729833462074168852;
    const double c58 = 0.79056941504209483300, c38 = 0.61237243569579452455;
    Y[0] = 1.0;
    Y[1] = s3*x;  Y[2] = s3*y;  Y[3] = s3*z;
    Y[4] = s5*s3*x*z;  Y[5] = s5*s3*x*y;
    Y[6] = s5*(y*y - 0.5*(x*x + z*z));
    Y[7] = s5*s3*y*z;  Y[8] = s5*(s3/2.0)*(z*z - x*x);
    Y[9] = s7*c58*x*(3.0*z*z - x*x);
    Y[10]= s7*s15*x*y*z;
    Y[11]= s7*c38*x*(5.0*y*y - 1.0);
    Y[12]= s7*0.5*y*(5.0*y*y - 3.0);
    Y[13]= s7*c38*z*(5.0*y*y - 1.0);
    Y[14]= s7*(s15/2.0)*y*(z*z - x*x);
    Y[15]= s7*c58*z*(z*z - 3.0*x*x);
}

__device__ inline void sh_f32(float x, float y, float z, float* Y) {
    const float s3 = 1.73205080757f, s5 = 2.23606797750f, s7 = 2.64575131106f, s15 = 3.87298334621f;
    const float c58 = 0.79056941504f, c38 = 0.61237243570f;
    Y[0] = 1.0f;
    Y[1] = s3*x;  Y[2] = s3*y;  Y[3] = s3*z;
    Y[4] = s15*x*z;  Y[5] = s15*x*y;
    Y[6] = s5*(y*y - 0.5f*(x*x + z*z));
    Y[7] = s15*y*z;  Y[8] = s5*(s3*0.5f)*(z*z - x*x);
    Y[9] = s7*c58*x*(3.0f*z*z - x*x);
    Y[10]= s7*s15*x*y*z;
    Y[11]= s7*c38*x*(5.0f*y*y - 1.0f);
    Y[12]= s7*0.5f*y*(5.0f*y*y - 3.0f);
    Y[13]= s7*c38*z*(5.0f*y*y - 1.0f);
    Y[14]= s7*(s15*0.5f)*y*(z*z - x*x);
    Y[15]= s7*c58*z*(z*z - 3.0f*x*x);
}

__device__ inline unsigned short bf16rne(float x) {
    unsigned int u = __float_as_uint(x);
    unsigned int r = (u + 0x7FFFu + ((u >> 16) & 1u)) >> 16;
    return (unsigned short)r;
}
__device__ inline float bf16f(unsigned short h) {
    return __uint_as_float(((unsigned int)h) << 16);
}

// ---- setup: W3J tables (128-pt quadrature) + weight transpose + output zeroing ----
__global__ __launch_bounds__(512) void w3j_setup_kernel(
    const float* __restrict__ ww, const float* __restrict__ wb,
    float* __restrict__ g_w3j,
    unsigned short* __restrict__ Awhi, unsigned short* __restrict__ Awlo,
    unsigned short* __restrict__ Abhi, unsigned short* __restrict__ Ablo,
    float* __restrict__ out) {
    const int t = threadIdx.x;

    if (blockIdx.x >= N_PATHS) {   // zero-blocks
        const int b = blockIdx.x - N_PATHS;
        float4* o4 = (float4*)(out + (size_t)b * (N_NODES*FEAT/ZERO_BLOCKS));
#pragma unroll
        for (int r = 0; r < 4; ++r)
            o4[t + 512*r] = make_float4(0.f,0.f,0.f,0.f);
        return;
    }

    __shared__ float s_Yq[128][17];
    __shared__ float s_wq[128];
    __shared__ float s_part[256];
    __shared__ float red[256];
    __shared__ float s_scale;

    const int p = blockIdx.x;
    const int l1 = cL1[p], l2 = cL2[p];
    const int l3 = D_L3[p];
    const int d2 = 2*l2+1, d3 = 2*l3+1;
    const int csize = (2*l1+1)*d2*d3;
    const double step = 2.0*3.14159265358979323846/16.0;

    // weight transpose to A-layout [p][w][u], bf16 hi/lo split
#pragma unroll
    for (int r = 0; r < 2; ++r) {
        const int idx = t + 512*r;
        const int w = idx >> 5, u = idx & 31;
        const float vw = ww[p*1024 + u*32 + w];
        const float vb = wb[p*1024 + u*32 + w];
        const unsigned short hw = bf16rne(vw);
        const unsigned short hb = bf16rne(vb);
        const int o = p*1024 + w*32 + u;
        Awhi[o] = hw;  Awlo[o] = bf16rne(vw - bf16f(hw));
        Abhi[o] = hb;  Ablo[o] = bf16rne(vb - bf16f(hb));
    }

    // phase A: one quadrature point per thread (first 128 threads)
    if (t < 128) {
        const int iu = t >> 4, ip = t & 15;
        const double u = GLX8[iu];
        const double st = sqrt(fmax(1.0 - u*u, 0.0));
        double Y[16];
        sh_f64(st*COSP16[ip], st*SINP16[ip], u, Y);
#pragma unroll
        for (int i = 0; i < 16; ++i) s_Yq[t][i] = (float)Y[i];
        s_wq[t] = (float)(GLW8[iu] * step);
    }
    __syncthreads();

    // phase B: 4 threads/entry, 32 interleaved points each, shuffle-reduce
    const int entry0 = t >> 2, sub = t & 3;
#pragma unroll
    for (int pass = 0; pass < 2; ++pass) {
        const int entry = entry0 + pass*128;
        float acc = 0.f;
        if (entry < csize) {
            const int i = entry/(d2*d3); const int r = entry - i*(d2*d3);
            const int j = r/d3; const int k = r - j*d3;
            const int ai = l1*l1+i, bi = l2*l2+j, ci = l3*l3+k;
#pragma unroll 4
            for (int it = 0; it < 32; ++it) {
                const int q = it*4 + sub;
                acc = fmaf(s_wq[q] * s_Yq[q][ai] * s_Yq[q][bi], s_Yq[q][ci], acc);
            }
        }
        acc += __shfl_xor(acc, 1);
        acc += __shfl_xor(acc, 2);
        if (sub == 0 && entry < csize) s_part[entry] = acc;
    }
    __syncthreads();

    if (t < 256) { const float v = (t < csize) ? s_part[t] : 0.f; red[t] = v*v; }
    __syncthreads();
    for (int s = 128; s > 0; s >>= 1) {
        if (t < s) red[t] += red[t+s];
        __syncthreads();
    }
    if (t == 0) {
        const float pw = sqrtf((float)(2*l3+1) / ((float)CNT_L3[l3] * (float)HIDDEN));
        s_scale = pw / sqrtf(red[0]);
    }
    __syncthreads();
    if (t < csize) g_w3j[cCOFF[p] + t] = s_part[t] * s_scale;
}

// ---- one fully-unrolled path: z -> (A prefetch) -> tmp/stage -> 32x32 MFMA ----
template<int G, int P>
__device__ __forceinline__ void do_path(
    int lane, int el4, int u0, int bvaddr, int avaddr,
    const float (&xr0)[16], const float (&xr1)[16],
    const float* __restrict__ w3j,
    const unsigned short* __restrict__ Awhi, const unsigned short* __restrict__ Awlo,
    const unsigned short* __restrict__ Abhi, const unsigned short* __restrict__ Ablo,
    const float* sY, float* sz,
    unsigned short* sbh, unsigned short* sbl,
    f32x16 &Cw, f32x16 &Cb)
{
    constexpr int l1 = cL1[P], l2 = cL2[P];
    constexpr int d1 = 2*l1+1, d2 = 2*l2+1, d3 = 2*G+1;
    constexpr int zc = d1*d3;
    constexpr int xo = l1*l1;

    // z[el][i][k] = sum_j Y[el][l2^2+j] * C[i][j][k]   (4 edges; C via L1)
#pragma unroll
    for (int base = 0; base < 4*zc; base += 64) {
        const int idx = base + lane;
        if (idx < 4*zc) {
            const int elz = idx / zc;          // const-div
            const int r = idx - elz*zc;
            const int i = r / d3, k = r - i*d3;
            const float* Cp = w3j + cCOFF[P] + i*(d2*d3) + k;
            const float* Yp = sY + elz*16 + l2*l2;
            float acc = 0.f;
#pragma unroll
            for (int j = 0; j < d2; ++j) acc = fmaf(Yp[j], Cp[j*d3], acc);
            sz[elz*50 + r] = acc;
        }
    }
    WAVE_SYNC();

    // A-operand prefetch (global/L2) BEFORE the tmp VALU block hides its latency
    const unsigned short* pwh = Awhi + P*1024;
    const unsigned short* pwl = Awlo + P*1024;
    const unsigned short* pbh = Abhi + P*1024;
    const unsigned short* pbl = Ablo + P*1024;
    bf16x8 awh[2], awl[2], abh[2], abl[2];
#pragma unroll
    for (int kc = 0; kc < 2; ++kc) {
        awh[kc] = *(const bf16x8*)(pwh + avaddr + kc*16);
        awl[kc] = *(const bf16x8*)(pwl + avaddr + kc*16);
        abh[kc] = *(const bf16x8*)(pbh + avaddr + kc*16);
        abl[kc] = *(const bf16x8*)(pbl + avaddr + kc*16);
    }

    // tmp[u][k] = sum_i x[u,i]*z[i,k] for u=2u0,2u0+1; chop-split bf16; packed u32 stores
    {
        const float* zr = sz + el4*50;
        unsigned short* bh = sbh + (el4*d3)*40 + 2*u0;
        unsigned short* bl = sbl + (el4*d3)*40 + 2*u0;
#pragma unroll
        for (int k = 0; k < d3; ++k) {
            float t0 = 0.f, t1 = 0.f;
#pragma unroll
            for (int i = 0; i < d1; ++i) {
                const float zz = zr[i*d3 + k];
                t0 = fmaf(xr0[xo+i], zz, t0);
                t1 = fmaf(xr1[xo+i], zz, t1);
            }
            const unsigned int b0 = __float_as_uint(t0);
            const unsigned int b1 = __float_as_uint(t1);
            const float l0 = t0 - __uint_as_float(b0 & 0xFFFF0000u);
            const float l1f = t1 - __uint_as_float(b1 & 0xFFFF0000u);
            *(unsigned int*)(bh + k*40) = (b0 >> 16) | (b1 & 0xFFFF0000u);
            *(unsigned int*)(bl + k*40) = (__float_as_uint(l0) >> 16) | (__float_as_uint(l1f) & 0xFFFF0000u);
        }
    }
    WAVE_SYNC();

    // B loads + 12 MFMA (2 K-chunks x 3-pass hi/lo x {w,b}), interleaved dual chains
#pragma unroll
    for (int kc = 0; kc < 2; ++kc) {
        const bf16x8 bh = *(const bf16x8*)(sbh + bvaddr + kc*16);
        const bf16x8 bl = *(const bf16x8*)(sbl + bvaddr + kc*16);
        Cw = __builtin_amdgcn_mfma_f32_32x32x16_bf16(awh[kc], bh, Cw, 0, 0, 0);
        Cb = __builtin_amdgcn_mfma_f32_32x32x16_bf16(abh[kc], bh, Cb, 0, 0, 0);
        Cw = __builtin_amdgcn_mfma_f32_32x32x16_bf16(awh[kc], bl, Cw, 0, 0, 0);
        Cb = __builtin_amdgcn_mfma_f32_32x32x16_bf16(abh[kc], bl, Cb, 0, 0, 0);
        Cw = __builtin_amdgcn_mfma_f32_32x32x16_bf16(awl[kc], bh, Cw, 0, 0, 0);
        Cb = __builtin_amdgcn_mfma_f32_32x32x16_bf16(abl[kc], bh, Cb, 0, 0, 0);
    }
    WAVE_SYNC();  // B reads done before next path's stage overwrites
}

template<int G>
__device__ __forceinline__ void do_group(
    int lane, int el4, int u0, int bvaddr, int avaddr,
    const float (&xr0)[16], const float (&xr1)[16],
    const float* __restrict__ w3j,
    const unsigned short* __restrict__ Awhi, const unsigned short* __restrict__ Awlo,
    const unsigned short* __restrict__ Abhi, const unsigned short* __restrict__ Ablo,
    const float* sY, float* sz,
    unsigned short* sbh, unsigned short* sbl,
    const float* slen, float* smsg)
{
    constexpr int d3 = 2*G+1;
    constexpr int s = cL3S[G];
    constexpr int n = cL3S[G+1] - cL3S[G];
    f32x16 Cw = (f32x16)(0.f), Cb = (f32x16)(0.f);

    do_path<G, cL3P[s+0]>(lane,el4,u0,bvaddr,avaddr,xr0,xr1,w3j,Awhi,Awlo,Abhi,Ablo,sY,sz,sbh,sbl,Cw,Cb);
    do_path<G, cL3P[s+1]>(lane,el4,u0,bvaddr,avaddr,xr0,xr1,w3j,Awhi,Awlo,Abhi,Ablo,sY,sz,sbh,sbl,Cw,Cb);
    do_path<G, cL3P[s+2]>(lane,el4,u0,bvaddr,avaddr,xr0,xr1,w3j,Awhi,Awlo,Abhi,Ablo,sY,sz,sbh,sbl,Cw,Cb);
    do_path<G, cL3P[s+3]>(lane,el4,u0,bvaddr,avaddr,xr0,xr1,w3j,Awhi,Awlo,Abhi,Ablo,sY,sz,sbh,sbl,Cw,Cb);
    if constexpr (n > 4)
        do_path<G, cL3P[s+4]>(lane,el4,u0,bvaddr,avaddr,xr0,xr1,w3j,Awhi,Awlo,Abhi,Ablo,sY,sz,sbh,sbl,Cw,Cb);
    if constexpr (n > 5)
        do_path<G, cL3P[s+5]>(lane,el4,u0,bvaddr,avaddr,xr0,xr1,w3j,Awhi,Awlo,Abhi,Ablo,sY,sz,sbh,sbl,Cw,Cb);
    if constexpr (n > 6)
        do_path<G, cL3P[s+6]>(lane,el4,u0,bvaddr,avaddr,xr0,xr1,w3j,Awhi,Awlo,Abhi,Ablo,sY,sz,sbh,sbl,Cw,Cb);

    // epilogue: msg = len*Cw + Cb
    // C/D layout (verified m74/m101): col=lane&31, row=(reg&3)+8*(reg>>2)+4*(lane>>5)
    const int col = lane & 31;
    if (col < 4*d3) {
        const int elc = col / d3, k = col - elc*d3;   // const-div
        const float len = slen[elc];
        float* mp = smsg + elc*FEAT + cOFF3[G] + k;
#pragma unroll
        for (int reg = 0; reg < 16; ++reg) {
            const int w = (reg & 3) + 8*(reg >> 2) + 4*(lane >> 5);
            mp[w*d3] = fmaf(len, Cw[reg], Cb[reg]);
        }
    }
}

// ---- main: 2 waves/block, 4 edges/wave, 32x32x16 MFMA ----
__global__ __launch_bounds__(BLK) void edge_kernel(
    const float* __restrict__ nf,
    const int*   __restrict__ eidx,
    const float* __restrict__ ev,
    const float* __restrict__ w3j,
    const unsigned short* __restrict__ Awhi,
    const unsigned short* __restrict__ Awlo,
    const unsigned short* __restrict__ Abhi,
    const unsigned short* __restrict__ Ablo,
    float*       __restrict__ out)
{
    __shared__ float s_zp[2][200];
    __shared__ float s_Y[2][64];
    __shared__ float s_len[2][4];
    __shared__ int   s_src[2][4];
    __shared__ int   s_dst[2][4];
    __shared__ __align__(16) unsigned short s_Bhi[2][1280];  // [col(32)][u(32)+pad8]
    __shared__ __align__(16) unsigned short s_Blo[2][1280];
    __shared__ float s_msg[2][4*FEAT];

    const int t    = threadIdx.x;
    const int wave = t >> 6;
    const int lane = t & 63;
    const int el4  = lane >> 4;      // tmp-phase edge (4 per wave)
    const int u0   = lane & 15;      // tmp-phase u-pair index
    const int e0   = blockIdx.x * 8 + wave*4;
    const int bvaddr = (lane & 31)*40 + (lane >> 5)*8;   // B: n=lane&31, k0=(lane>>5)*8
    const int avaddr = (lane & 31)*32 + (lane >> 5)*8;   // A: m=lane&31, k0=(lane>>5)*8

    if (lane < 4) {
        const int e = e0 + lane;
        s_src[wave][lane] = eidx[e];
        s_dst[wave][lane] = eidx[N_EDGES + e];
        const float x = ev[e*3+0], y = ev[e*3+1], z = ev[e*3+2];
        const float len = sqrtf(x*x + y*y + z*z);
        const float lc = fmaxf(len, 1e-8f);
        s_len[wave][lane] = lc;
        float Yl[16];
        sh_f32(x/lc, y/lc, z/lc, Yl);
#pragma unroll
        for (int i = 0; i < 16; ++i) s_Y[wave][lane*16+i] = Yl[i];
    }
    WAVE_SYNC();

    // preload this lane's 2 u-rows of x (u = 2u0, 2u0+1) into registers
    float xr0[16], xr1[16];
    {
        const float* xrow = nf + (size_t)s_src[wave][el4]*FEAT;
        const int ua = 2*u0, ub = 2*u0 + 1;
        xr0[0] = xrow[ua];                 xr1[0] = xrow[ub];
#pragma unroll
        for (int i = 0; i < 3; ++i) { xr0[1+i] = xrow[32 + ua*3 + i];  xr1[1+i] = xrow[32 + ub*3 + i]; }
#pragma unroll
        for (int i = 0; i < 5; ++i) { xr0[4+i] = xrow[128 + ua*5 + i]; xr1[4+i] = xrow[128 + ub*5 + i]; }
#pragma unroll
        for (int i = 0; i < 7; ++i) { xr0[9+i] = xrow[288 + ua*7 + i]; xr1[9+i] = xrow[288 + ub*7 + i]; }
    }

    do_group<0>(lane,el4,u0,bvaddr,avaddr,xr0,xr1,w3j,Awhi,Awlo,Abhi,Ablo,
                s_Y[wave], s_zp[wave], s_Bhi[wave], s_Blo[wave], s_len[wave], s_msg[wave]);
    do_group<1>(lane,el4,u0,bvaddr,avaddr,xr0,xr1,w3j,Awhi,Awlo,Abhi,Ablo,
                s_Y[wave], s_zp[wave], s_Bhi[wave], s_Blo[wave], s_len[wave], s_msg[wave]);
    do_group<2>(lane,el4,u0,bvaddr,avaddr,xr0,xr1,w3j,Awhi,Awlo,Abhi,Ablo,
                s_Y[wave], s_zp[wave], s_Bhi[wave], s_Blo[wave], s_len[wave], s_msg[wave]);
    do_group<3>(lane,el4,u0,bvaddr,avaddr,xr0,xr1,w3j,Awhi,Awlo,Abhi,Ablo,
                s_Y[wave], s_zp[wave], s_Bhi[wave], s_Blo[wave], s_len[wave], s_msg[wave]);
    WAVE_SYNC();

    // wave-local coalesced scatter: 4 edges x 512
    for (int i = lane; i < 4*FEAT; i += 64) {
        const int elc = i >> 9, m = i & 511;
        atomicAdd(&out[(size_t)s_dst[wave][elc]*FEAT + m], s_msg[wave][i]);
    }
}

extern "C" void kernel_launch(void* const* d_in, const int* in_sizes, int n_in,
                              void* d_out, int out_size, void* d_ws, size_t ws_size,
                              hipStream_t stream) {
    const float* nf   = (const float*)d_in[0];
    const int*   eidx = (const int*)  d_in[1];
    const float* ev   = (const float*)d_in[2];
    const float* ww   = (const float*)d_in[3];
    const float* wb   = (const float*)d_in[4];
    float* out = (float*)d_out;

    float* w3j = (float*)d_ws;                                   // 7500 B
    unsigned short* Awhi = (unsigned short*)((char*)d_ws + 16384);
    unsigned short* Awlo = Awhi + N_PATHS*1024;
    unsigned short* Abhi = Awlo + N_PATHS*1024;
    unsigned short* Ablo = Abhi + N_PATHS*1024;                  // ends at 204800 B

    w3j_setup_kernel<<<N_PATHS + ZERO_BLOCKS, 512, 0, stream>>>(
        ww, wb, w3j, Awhi, Awlo, Abhi, Ablo, out);
    edge_kernel<<<N_EDGES/8, BLK, 0, stream>>>(nf, eidx, ev, w3j, Awhi, Awlo, Abhi, Ablo, out);
}

// Round 14
// 120.896 us; speedup vs baseline: 1.3008x; 1.0039x over previous
//
#include <hip/hip_runtime.h>
#include <math.h>

#define N_PATHS 23
#define HIDDEN  32
#define N_NODES 4096
#define N_EDGES 8192
#define FEAT    512
#define BLK     128   // 2 waves; 4 edges per wave (R11 structure)
#define ZERO_BLOCKS 256

// wave-local LDS phase separator (all prior DS ops complete)
#define WAVE_SYNC() asm volatile("s_waitcnt lgkmcnt(0)" ::: "memory")

typedef __attribute__((ext_vector_type(8)))  short bf16x8;
typedef __attribute__((ext_vector_type(16))) float f32x16;

// ---- compile-time path metadata (PATHS enumeration: l1 outer, l2, l3) ----
constexpr int cL1[N_PATHS] = {0,0,0,0, 1,1,1,1,1,1, 2,2,2,2,2,2,2, 3,3,3,3,3,3};
constexpr int cL2[N_PATHS] = {0,1,2,3, 0,1,1,2,2,3, 0,1,1,2,2,3,3, 0,1,2,2,3,3};
constexpr int cCOFF[N_PATHS]= {0,1,10,35,84,93,102,147,192,297,402,427,472,577,602,727,832,1077,1126,1231,1336,1581,1630};
constexpr int cL3P[N_PATHS] = {0,5,13,21, 1,4,7,11,15,19, 2,6,9,10,14,18,22, 3,8,12,16,17,20};
constexpr int cL3S[5] = {0,4,10,17,23};
constexpr int cOFF3[4] = {0,32,128,288};
__device__ const int CNT_L3[4] = {4,6,7,6};
__device__ const int D_L3[N_PATHS] = {0,1,2,3, 1,0,2,1,3,2, 2,1,3,0,2,1,3, 3,2,1,3,0,2};

// per-edge z offset of path slot pi within its group's batched z buffer
constexpr int zOff(int G, int pi) {
    int off = 0;
    for (int q = cL3S[G]; q < pi; ++q) off += (2*cL1[cL3P[q]]+1)*(2*G+1);
    return off;
}
// max per-edge z total over groups: G3 = 7+21+35+35+49+49 = 196 -> 4*196 = 784 floats

// ---- 8-point Gauss-Legendre nodes/weights (128-pt rule: exact for degree<=9 SH triple products) ----
__device__ const double GLX8[8] = {
    -0.96028985649753623168, -0.79666647741362673959, -0.52553240991632898582, -0.18343464249564980494,
     0.18343464249564980494,  0.52553240991632898582,  0.79666647741362673959,  0.96028985649753623168};
__device__ const double GLW8[8] = {
     0.10122853629037625915,  0.22238103445337447054,  0.31370664587788728734,  0.36268378337836198297,
     0.36268378337836198297,  0.31370664587788728734,  0.22238103445337447054,  0.10122853629037625915};
// cos/sin(k*pi/8), k=0..15 — exact literals
__device__ const double COSP16[16] = {
  1.0,                     0.92387953251128675613,  0.70710678118654752440,  0.38268343236508977173,
  0.0,                    -0.38268343236508977173, -0.70710678118654752440, -0.92387953251128675613,
 -1.0,                    -0.92387953251128675613, -0.70710678118654752440, -0.38268343236508977173,
  0.0,                     0.38268343236508977173,  0.70710678118654752440,  0.92387953251128675613};
__device__ const double SINP16[16] = {
  0.0,                     0.38268343236508977173,  0.70710678118654752440,  0.92387953251128675613,
  1.0,                     0.92387953251128675613,  0.70710678118654752440,  0.38268343236508977173,
  0.0,                    -0.38268343236508977173, -0.70710678118654752440, -0.92387953251128675613,
 -1.0,                    -0.92387953251128675613, -0.70710678118654752440, -0.38268343236508977173};

__device__ inline void sh_f64(double x, double y, double z, double* Y) {
    const double s3 = 1.7320508075688772935, s5 = 2.2360679774997896964,
                 s7 = 2.6457513110645905905, s15 = 3.8729833462074168852;
    const double c58 = 0.79056941504209483300, c38 = 0.61237243569579452455;
    Y[0] = 1.0;
    Y[1] = s3*x;  Y[2] = s3*y;  Y[3] = s3*z;
    Y[4] = s5*s3*x*z;  Y[5] = s5*s3*x*y;
    Y[6] = s5*(y*y - 0.5*(x*x + z*z));
    Y[7] = s5*s3*y*z;  Y[8] = s5*(s3/2.0)*(z*z - x*x);
    Y[9] = s7*c58*x*(3.0*z*z - x*x);
    Y[10]= s7*s15*x*y*z;
    Y[11]= s7*c38*x*(5.0*y*y - 1.0);
    Y[12]= s7*0.5*y*(5.0*y*y - 3.0);
    Y[13]= s7*c38*z*(5.0*y*y - 1.0);
    Y[14]= s7*(s15/2.0)*y*(z*z - x*x);
    Y[15]= s7*c58*z*(z*z - 3.0*x*x);
}

__device__ inline void sh_f32(float x, float y, float z, float* Y) {
    const float s3 = 1.73205080757f, s5 = 2.23606797750f, s7 = 2.64575131106f, s15 = 3.87298334621f;
    const float c58 = 0.79056941504f, c38 = 0.61237243570f;
    Y[0] = 1.0f;
    Y[1] = s3*x;  Y[2] = s3*y;  Y[3] = s3*z;
    Y[4] = s15*x*z;  Y[5] = s15*x*y;
    Y[6] = s5*(y*y - 0.5f*(x*x + z*z));
    Y[7] = s15*y*z;  Y[8] = s5*(s3*0.5f)*(z*z - x*x);
    Y[9] = s7*c58*x*(3.0f*z*z - x*x);
    Y[10]= s7*s15*x*y*z;
    Y[11]= s7*c38*x*(5.0f*y*y - 1.0f);
    Y[12]= s7*0.5f*y*(5.0f*y*y - 3.0f);
    Y[13]= s7*c38*z*(5.0f*y*y - 1.0f);
    Y[14]= s7*(s15*0.5f)*y*(z*z - x*x);
    Y[15]= s7*c58*z*(z*z - 3.0f*x*x);
}

__device__ inline unsigned short bf16rne(float x) {
    unsigned int u = __float_as_uint(x);
    unsigned int r = (u + 0x7FFFu + ((u >> 16) & 1u)) >> 16;
    return (unsigned short)r;
}
__device__ inline float bf16f(unsigned short h) {
    return __uint_as_float(((unsigned int)h) << 16);
}

// ---- setup: W3J tables (128-pt quadrature) + weight transpose + output zeroing ----
__global__ __launch_bounds__(512) void w3j_setup_kernel(
    const float* __restrict__ ww, const float* __restrict__ wb,
    float* __restrict__ g_w3j,
    unsigned short* __restrict__ Awhi, unsigned short* __restrict__ Awlo,
    unsigned short* __restrict__ Abhi, unsigned short* __restrict__ Ablo,
    float* __restrict__ out) {
    const int t = threadIdx.x;

    if (blockIdx.x >= N_PATHS) {   // zero-blocks
        const int b = blockIdx.x - N_PATHS;
        float4* o4 = (float4*)(out + (size_t)b * (N_NODES*FEAT/ZERO_BLOCKS));
#pragma unroll
        for (int r = 0; r < 4; ++r)
            o4[t + 512*r] = make_float4(0.f,0.f,0.f,0.f);
        return;
    }

    __shared__ float s_Yq[128][17];
    __shared__ float s_wq[128];
    __shared__ float s_part[256];
    __shared__ float red[256];
    __shared__ float s_scale;

    const int p = blockIdx.x;
    const int l1 = cL1[p], l2 = cL2[p];
    const int l3 = D_L3[p];
    const int d2 = 2*l2+1, d3 = 2*l3+1;
    const int csize = (2*l1+1)*d2*d3;
    const double step = 2.0*3.14159265358979323846/16.0;

    // weight transpose to A-layout [p][w][u], bf16 hi/lo split
#pragma unroll
    for (int r = 0; r < 2; ++r) {
        const int idx = t + 512*r;
        const int w = idx >> 5, u = idx & 31;
        const float vw = ww[p*1024 + u*32 + w];
        const float vb = wb[p*1024 + u*32 + w];
        const unsigned short hw = bf16rne(vw);
        const unsigned short hb = bf16rne(vb);
        const int o = p*1024 + w*32 + u;
        Awhi[o] = hw;  Awlo[o] = bf16rne(vw - bf16f(hw));
        Abhi[o] = hb;  Ablo[o] = bf16rne(vb - bf16f(hb));
    }

    // phase A: one quadrature point per thread (first 128 threads)
    if (t < 128) {
        const int iu = t >> 4, ip = t & 15;
        const double u = GLX8[iu];
        const double st = sqrt(fmax(1.0 - u*u, 0.0));
        double Y[16];
        sh_f64(st*COSP16[ip], st*SINP16[ip], u, Y);
#pragma unroll
        for (int i = 0; i < 16; ++i) s_Yq[t][i] = (float)Y[i];
        s_wq[t] = (float)(GLW8[iu] * step);
    }
    __syncthreads();

    // phase B: 4 threads/entry, 32 interleaved points each, shuffle-reduce
    const int entry0 = t >> 2, sub = t & 3;
#pragma unroll
    for (int pass = 0; pass < 2; ++pass) {
        const int entry = entry0 + pass*128;
        float acc = 0.f;
        if (entry < csize) {
            const int i = entry/(d2*d3); const int r = entry - i*(d2*d3);
            const int j = r/d3; const int k = r - j*d3;
            const int ai = l1*l1+i, bi = l2*l2+j, ci = l3*l3+k;
#pragma unroll 4
            for (int it = 0; it < 32; ++it) {
                const int q = it*4 + sub;
                acc = fmaf(s_wq[q] * s_Yq[q][ai] * s_Yq[q][bi], s_Yq[q][ci], acc);
            }
        }
        acc += __shfl_xor(acc, 1);
        acc += __shfl_xor(acc, 2);
        if (sub == 0 && entry < csize) s_part[entry] = acc;
    }
    __syncthreads();

    if (t < 256) { const float v = (t < csize) ? s_part[t] : 0.f; red[t] = v*v; }
    __syncthreads();
    for (int s = 128; s > 0; s >>= 1) {
        if (t < s) red[t] += red[t+s];
        __syncthreads();
    }
    if (t == 0) {
        const float pw = sqrtf((float)(2*l3+1) / ((float)CNT_L3[l3] * (float)HIDDEN));
        s_scale = pw / sqrtf(red[0]);
    }
    __syncthreads();
    if (t < csize) g_w3j[cCOFF[p] + t] = s_part[t] * s_scale;
}

// ---- batched z for one path (no sync): z[el][i][k] into group z buffer ----
template<int G, int P, int ZOFF>
__device__ __forceinline__ void do_zpath(
    int lane, const float* __restrict__ w3j, const float* sY, float* sz)
{
    constexpr int l1 = cL1[P], l2 = cL2[P];
    constexpr int d1 = 2*l1+1, d2 = 2*l2+1, d3 = 2*G+1;
    constexpr int zc = d1*d3;
#pragma unroll
    for (int base = 0; base < 4*zc; base += 64) {
        const int idx = base + lane;
        if (idx < 4*zc) {
            const int elz = idx / zc;          // const-div
            const int r = idx - elz*zc;
            const int i = r / d3, k = r - i*d3;
            const float* Cp = w3j + cCOFF[P] + i*(d2*d3) + k;
            const float* Yp = sY + elz*16 + l2*l2;
            float acc = 0.f;
#pragma unroll
            for (int j = 0; j < d2; ++j) acc = fmaf(Yp[j], Cp[j*d3], acc);
            sz[4*ZOFF + elz*zc + r] = acc;
        }
    }
}

// ---- one path: A prefetch -> tmp/stage -> 32x32 MFMA (z pre-computed) ----
template<int G, int P, int ZOFF>
__device__ __forceinline__ void do_path(
    int lane, int el4, int u0, int bvaddr, int avaddr,
    const float (&xr0)[16], const float (&xr1)[16],
    const unsigned short* __restrict__ Awhi, const unsigned short* __restrict__ Awlo,
    const unsigned short* __restrict__ Abhi, const unsigned short* __restrict__ Ablo,
    const float* sz,
    unsigned short* sbh, unsigned short* sbl,
    f32x16 &Cw, f32x16 &Cb)
{
    constexpr int l1 = cL1[P];
    constexpr int d1 = 2*l1+1, d3 = 2*G+1;
    constexpr int zc = d1*d3;
    constexpr int xo = l1*l1;

    // A-operand prefetch (global/L2) BEFORE the tmp VALU block hides its latency
    const unsigned short* pwh = Awhi + P*1024;
    const unsigned short* pwl = Awlo + P*1024;
    const unsigned short* pbh = Abhi + P*1024;
    const unsigned short* pbl = Ablo + P*1024;
    bf16x8 awh[2], awl[2], abh[2], abl[2];
#pragma unroll
    for (int kc = 0; kc < 2; ++kc) {
        awh[kc] = *(const bf16x8*)(pwh + avaddr + kc*16);
        awl[kc] = *(const bf16x8*)(pwl + avaddr + kc*16);
        abh[kc] = *(const bf16x8*)(pbh + avaddr + kc*16);
        abl[kc] = *(const bf16x8*)(pbl + avaddr + kc*16);
    }

    // tmp[u][k] = sum_i x[u,i]*z[i,k] for u=2u0,2u0+1; chop-split bf16; packed u32 stores
    {
        const float* zr = sz + 4*ZOFF + el4*zc;
        unsigned short* bh = sbh + (el4*d3)*40 + 2*u0;
        unsigned short* bl = sbl + (el4*d3)*40 + 2*u0;
#pragma unroll
        for (int k = 0; k < d3; ++k) {
            float t0 = 0.f, t1 = 0.f;
#pragma unroll
            for (int i = 0; i < d1; ++i) {
                const float zz = zr[i*d3 + k];
                t0 = fmaf(xr0[xo+i], zz, t0);
                t1 = fmaf(xr1[xo+i], zz, t1);
            }
            const unsigned int b0 = __float_as_uint(t0);
            const unsigned int b1 = __float_as_uint(t1);
            const float l0 = t0 - __uint_as_float(b0 & 0xFFFF0000u);
            const float l1f = t1 - __uint_as_float(b1 & 0xFFFF0000u);
            *(unsigned int*)(bh + k*40) = (b0 >> 16) | (b1 & 0xFFFF0000u);
            *(unsigned int*)(bl + k*40) = (__float_as_uint(l0) >> 16) | (__float_as_uint(l1f) & 0xFFFF0000u);
        }
    }
    WAVE_SYNC();

    // B loads + 12 MFMA (2 K-chunks x 3-pass hi/lo x {w,b}), interleaved dual chains
#pragma unroll
    for (int kc = 0; kc < 2; ++kc) {
        const bf16x8 bh = *(const bf16x8*)(sbh + bvaddr + kc*16);
        const bf16x8 bl = *(const bf16x8*)(sbl + bvaddr + kc*16);
        Cw = __builtin_amdgcn_mfma_f32_32x32x16_bf16(awh[kc], bh, Cw, 0, 0, 0);
        Cb = __builtin_amdgcn_mfma_f32_32x32x16_bf16(abh[kc], bh, Cb, 0, 0, 0);
        Cw = __builtin_amdgcn_mfma_f32_32x32x16_bf16(awh[kc], bl, Cw, 0, 0, 0);
        Cb = __builtin_amdgcn_mfma_f32_32x32x16_bf16(abh[kc], bl, Cb, 0, 0, 0);
        Cw = __builtin_amdgcn_mfma_f32_32x32x16_bf16(awl[kc], bh, Cw, 0, 0, 0);
        Cb = __builtin_amdgcn_mfma_f32_32x32x16_bf16(abl[kc], bh, Cb, 0, 0, 0);
    }
    WAVE_SYNC();  // B reads done before next path's stage overwrites
}

// ---- one l3 group: batched z (1 sync), then per-path tmp+MFMA; epilogue into s_msg ----
template<int G>
__device__ __forceinline__ void do_group(
    int lane, int el4, int u0, int bvaddr, int avaddr,
    const float (&xr0)[16], const float (&xr1)[16],
    const float* __restrict__ w3j,
    const unsigned short* __restrict__ Awhi, const unsigned short* __restrict__ Awlo,
    const unsigned short* __restrict__ Abhi, const unsigned short* __restrict__ Ablo,
    const float* sY, float* sz,
    unsigned short* sbh, unsigned short* sbl,
    const float* slen, float* smsg)
{
    constexpr int d3 = 2*G+1;
    constexpr int s = cL3S[G];
    constexpr int n = cL3S[G+1] - cL3S[G];
    f32x16 Cw = (f32x16)(0.f), Cb = (f32x16)(0.f);

    // batched z: all paths of the group, single sync
    do_zpath<G, cL3P[s+0], zOff(G,s+0)>(lane, w3j, sY, sz);
    do_zpath<G, cL3P[s+1], zOff(G,s+1)>(lane, w3j, sY, sz);
    do_zpath<G, cL3P[s+2], zOff(G,s+2)>(lane, w3j, sY, sz);
    do_zpath<G, cL3P[s+3], zOff(G,s+3)>(lane, w3j, sY, sz);
    if constexpr (n > 4) do_zpath<G, cL3P[s+4], zOff(G,s+4)>(lane, w3j, sY, sz);
    if constexpr (n > 5) do_zpath<G, cL3P[s+5], zOff(G,s+5)>(lane, w3j, sY, sz);
    if constexpr (n > 6) do_zpath<G, cL3P[s+6], zOff(G,s+6)>(lane, w3j, sY, sz);
    WAVE_SYNC();

    do_path<G, cL3P[s+0], zOff(G,s+0)>(lane,el4,u0,bvaddr,avaddr,xr0,xr1,Awhi,Awlo,Abhi,Ablo,sz,sbh,sbl,Cw,Cb);
    do_path<G, cL3P[s+1], zOff(G,s+1)>(lane,el4,u0,bvaddr,avaddr,xr0,xr1,Awhi,Awlo,Abhi,Ablo,sz,sbh,sbl,Cw,Cb);
    do_path<G, cL3P[s+2], zOff(G,s+2)>(lane,el4,u0,bvaddr,avaddr,xr0,xr1,Awhi,Awlo,Abhi,Ablo,sz,sbh,sbl,Cw,Cb);
    do_path<G, cL3P[s+3], zOff(G,s+3)>(lane,el4,u0,bvaddr,avaddr,xr0,xr1,Awhi,Awlo,Abhi,Ablo,sz,sbh,sbl,Cw,Cb);
    if constexpr (n > 4)
        do_path<G, cL3P[s+4], zOff(G,s+4)>(lane,el4,u0,bvaddr,avaddr,xr0,xr1,Awhi,Awlo,Abhi,Ablo,sz,sbh,sbl,Cw,Cb);
    if constexpr (n > 5)
        do_path<G, cL3P[s+5], zOff(G,s+5)>(lane,el4,u0,bvaddr,avaddr,xr0,xr1,Awhi,Awlo,Abhi,Ablo,sz,sbh,sbl,Cw,Cb);
    if constexpr (n > 6)
        do_path<G, cL3P[s+6], zOff(G,s+6)>(lane,el4,u0,bvaddr,avaddr,xr0,xr1,Awhi,Awlo,Abhi,Ablo,sz,sbh,sbl,Cw,Cb);

    // epilogue: msg = len*Cw + Cb
    // C/D layout (verified m74/m101): col=lane&31, row=(reg&3)+8*(reg>>2)+4*(lane>>5)
    const int col = lane & 31;
    if (col < 4*d3) {
        const int elc = col / d3, k = col - elc*d3;   // const-div
        const float len = slen[elc];
        float* mp = smsg + elc*FEAT + cOFF3[G] + k;
#pragma unroll
        for (int reg = 0; reg < 16; ++reg) {
            const int w = (reg & 3) + 8*(reg >> 2) + 4*(lane >> 5);
            mp[w*d3] = fmaf(len, Cw[reg], Cb[reg]);
        }
    }
}

// ---- main: 2 waves/block, 4 edges/wave, 32x32x16 MFMA (R11 structure) ----
__global__ __launch_bounds__(BLK) void edge_kernel(
    const float* __restrict__ nf,
    const int*   __restrict__ eidx,
    const float* __restrict__ ev,
    const float* __restrict__ w3j,
    const unsigned short* __restrict__ Awhi,
    const unsigned short* __restrict__ Awlo,
    const unsigned short* __restrict__ Abhi,
    const unsigned short* __restrict__ Ablo,
    float*       __restrict__ out)
{
    __shared__ float s_zp[2][784];       // batched per-group z (max G3: 4*196)
    __shared__ float s_Y[2][64];
    __shared__ float s_len[2][4];
    __shared__ int   s_src[2][4];
    __shared__ int   s_dst[2][4];
    __shared__ __align__(16) unsigned short s_Bhi[2][1280];  // [col(32)][u(32)+pad8]
    __shared__ __align__(16) unsigned short s_Blo[2][1280];
    __shared__ float s_msg[2][4*FEAT];

    const int t    = threadIdx.x;
    const int wave = t >> 6;
    const int lane = t & 63;
    const int el4  = lane >> 4;      // tmp-phase edge (4 per wave)
    const int u0   = lane & 15;      // tmp-phase u-pair index
    const int e0   = blockIdx.x * 8 + wave*4;
    const int bvaddr = (lane & 31)*40 + (lane >> 5)*8;   // B: n=lane&31, k0=(lane>>5)*8
    const int avaddr = (lane & 31)*32 + (lane >> 5)*8;   // A: m=lane&31, k0=(lane>>5)*8

    if (lane < 4) {
        const int e = e0 + lane;
        s_src[wave][lane] = eidx[e];
        s_dst[wave][lane] = eidx[N_EDGES + e];
        const float x = ev[e*3+0], y = ev[e*3+1], z = ev[e*3+2];
        const float len = sqrtf(x*x + y*y + z*z);
        const float lc = fmaxf(len, 1e-8f);
        s_len[wave][lane] = lc;
        float Yl[16];
        sh_f32(x/lc, y/lc, z/lc, Yl);
#pragma unroll
        for (int i = 0; i < 16; ++i) s_Y[wave][lane*16+i] = Yl[i];
    }
    WAVE_SYNC();

    // preload this lane's 2 u-rows of x (u = 2u0, 2u0+1) into registers
    float xr0[16], xr1[16];
    {
        const float* xrow = nf + (size_t)s_src[wave][el4]*FEAT;
        const int ua = 2*u0, ub = 2*u0 + 1;
        xr0[0] = xrow[ua];                 xr1[0] = xrow[ub];
#pragma unroll
        for (int i = 0; i < 3; ++i) { xr0[1+i] = xrow[32 + ua*3 + i];  xr1[1+i] = xrow[32 + ub*3 + i]; }
#pragma unroll
        for (int i = 0; i < 5; ++i) { xr0[4+i] = xrow[128 + ua*5 + i]; xr1[4+i] = xrow[128 + ub*5 + i]; }
#pragma unroll
        for (int i = 0; i < 7; ++i) { xr0[9+i] = xrow[288 + ua*7 + i]; xr1[9+i] = xrow[288 + ub*7 + i]; }
    }

    do_group<0>(lane,el4,u0,bvaddr,avaddr,xr0,xr1,w3j,Awhi,Awlo,Abhi,Ablo,
                s_Y[wave], s_zp[wave], s_Bhi[wave], s_Blo[wave], s_len[wave], s_msg[wave]);
    do_group<1>(lane,el4,u0,bvaddr,avaddr,xr0,xr1,w3j,Awhi,Awlo,Abhi,Ablo,
                s_Y[wave], s_zp[wave], s_Bhi[wave], s_Blo[wave], s_len[wave], s_msg[wave]);
    do_group<2>(lane,el4,u0,bvaddr,avaddr,xr0,xr1,w3j,Awhi,Awlo,Abhi,Ablo,
                s_Y[wave], s_zp[wave], s_Bhi[wave], s_Blo[wave], s_len[wave], s_msg[wave]);
    do_group<3>(lane,el4,u0,bvaddr,avaddr,xr0,xr1,w3j,Awhi,Awlo,Abhi,Ablo,
                s_Y[wave], s_zp[wave], s_Bhi[wave], s_Blo[wave], s_len[wave], s_msg[wave]);
    WAVE_SYNC();

    // wave-local coalesced scatter: 4 edges x 512 (R11 actor pattern)
    for (int i = lane; i < 4*FEAT; i += 64) {
        const int elc = i >> 9, m = i & 511;
        atomicAdd(&out[(size_t)s_dst[wave][elc]*FEAT + m], s_msg[wave][i]);
    }
}

extern "C" void kernel_launch(void* const* d_in, const int* in_sizes, int n_in,
                              void* d_out, int out_size, void* d_ws, size_t ws_size,
                              hipStream_t stream) {
    const float* nf   = (const float*)d_in[0];
    const int*   eidx = (const int*)  d_in[1];
    const float* ev   = (const float*)d_in[2];
    const float* ww   = (const float*)d_in[3];
    const float* wb   = (const float*)d_in[4];
    float* out = (float*)d_out;

    float* w3j = (float*)d_ws;                                   // 7500 B
    unsigned short* Awhi = (unsigned short*)((char*)d_ws + 16384);
    unsigned short* Awlo = Awhi + N_PATHS*1024;
    unsigned short* Abhi = Awlo + N_PATHS*1024;
    unsigned short* Ablo = Abhi + N_PATHS*1024;                  // ends at 204800 B

    w3j_setup_kernel<<<N_PATHS + ZERO_BLOCKS, 512, 0, stream>>>(
        ww, wb, w3j, Awhi, Awlo, Abhi, Ablo, out);
    edge_kernel<<<N_EDGES/8, BLK, 0, stream>>>(nf, eidx, ev, w3j, Awhi, Awlo, Abhi, Ablo, out);
}